// Round 10
// baseline (183.405 us; speedup 1.0000x reference)
//
#include <hip/hip_runtime.h>

// Flash attention fwd: fp32 I/O, bf16 MFMA, fp32 softmax math.
// BH=32, S=2048, D=64, additive mask [2,S,S] tiled bh%2.
// R10: S^T orientation (QK: A=K, B=Q) so P has q-rows on lanes; PV A-frags
// built in-register via ds_bpermute with BOTH nt-planes packed as bf16x2 in
// the 32-bit payload (fixes R9: two dest quads pull the same src lane but
// need different planes -> carry both, select by dest lane bit 5).
// No sP LDS (32 KB total), float4 mask loads, scalar lsum per m-group.
// Base: R7 structure (4 waves x 32 q-rows, K/V dbuf, 1 barrier/tile).

constexpr int cBH = 32;
constexpr int cS  = 2048;
constexpr int cD  = 64;
constexpr int cQT = 128;            // 4 waves x 32 q-rows
constexpr int cNT = cS / 64;        // 32 k-tiles

typedef __bf16 bf16x8 __attribute__((ext_vector_type(8)));
typedef __bf16 bf16x4 __attribute__((ext_vector_type(4)));
typedef float  f32x4  __attribute__((ext_vector_type(4)));

__device__ __forceinline__ unsigned short bfbits(float f) {
    return __builtin_bit_cast(unsigned short, (__bf16)f);
}
__device__ __forceinline__ bf16x4 pack4(f32x4 a) {
    bf16x4 r;
    r[0] = (__bf16)a[0]; r[1] = (__bf16)a[1];
    r[2] = (__bf16)a[2]; r[3] = (__bf16)a[3];
    return r;
}
__device__ __forceinline__ bf16x8 pack8s(f32x4 a, f32x4 b, float s) {
    bf16x8 r;
    r[0] = (__bf16)(a[0]*s); r[1] = (__bf16)(a[1]*s);
    r[2] = (__bf16)(a[2]*s); r[3] = (__bf16)(a[3]*s);
    r[4] = (__bf16)(b[0]*s); r[5] = (__bf16)(b[1]*s);
    r[6] = (__bf16)(b[2]*s); r[7] = (__bf16)(b[3]*s);
    return r;
}
__device__ __forceinline__ int gkey(int d) {     // sV swizzle key
    return (d ^ (d >> 3)) & 7;
}

__global__ __launch_bounds__(256, 2)
void sdpa_flash_kernel(const float* __restrict__ q,
                       const float* __restrict__ k,
                       const float* __restrict__ v,
                       const float* __restrict__ mask,
                       float* __restrict__ out)
{
    // sK: [krow][d] bf16, key krow&7.  sV: [d][krow] (V^T) bf16, key gkey(d).
    __shared__ unsigned short sK[2][64 * 64];
    __shared__ unsigned short sV[2][64 * 64];

    const int tid  = threadIdx.x;
    const int wv   = tid >> 6;
    const int lane = tid & 63;
    const int quad = lane >> 4;
    const int ln   = lane & 15;

    const int fid = blockIdx.x;
    const int bh  = (fid & 7) | ((fid >> 7) << 3);     // XCD-local heads
    const int qb  = ((fid >> 3) & 15) * cQT;
    const int mb  = bh & 1;

    const float L2E = 1.4426950408889634f;

    // ---- Q fragments, pre-scaled by 0.125*log2(e): aq[mg][ks].
    // Lane map (n=ln, k=quad*8+j) is exactly the MFMA B-operand layout. ----
    bf16x8 aq[2][2];
#pragma unroll
    for (int mg = 0; mg < 2; ++mg) {
        const float* qp = q + ((size_t)bh * cS + qb + wv * 32 + mg * 16 + ln) * cD + quad * 8;
        aq[mg][0] = pack8s(*(const f32x4*)(qp),      *(const f32x4*)(qp + 4),  0.125f * L2E);
        aq[mg][1] = pack8s(*(const f32x4*)(qp + 32), *(const f32x4*)(qp + 36), 0.125f * L2E);
    }

    f32x4 acc[2][4];
    float lsum[2] = {0.f, 0.f};
#pragma unroll
    for (int mg = 0; mg < 2; ++mg)
#pragma unroll
        for (int t = 0; t < 4; ++t)
            acc[mg][t] = (f32x4){0.f, 0.f, 0.f, 0.f};

    // ---- staging geometry: 256 threads; chunk j = floats j*1024 + tid*4 ----
    const int sr0 = tid >> 4;                 // 0..15
    const int c4  = (tid & 15) << 2;
    const int ka0 = sr0 * 64 + (((c4 >> 3) ^ (sr0 & 7)) << 3) + (c4 & 7);
    const float* kg = k + (size_t)bh * cS * cD;
    const float* vg = v + (size_t)bh * cS * cD;

    // per-lane mask row pointers: row = qb+wv*32+mg*16+ln, col base quad*4
    const float* mrow0 = mask + (size_t)mb * cS * cS
                              + (size_t)(qb + wv * 32 + ln) * cS + quad * 4;
    const float* mrow1 = mrow0 + (size_t)16 * cS;

    // bpermute src-lane byte addrs: fA (j<4): lane (quad&1)*32 + ln; fB: +16
    const int permA = ((((lane >> 4) & 1) << 5) + ln) << 2;
    const int permB = permA + 64;
    const int shft  = (lane & 32) >> 1;       // dest quad>>1: 0 -> lo, 1 -> hi

    // ---- stage tile 0 ----
#pragma unroll
    for (int j = 0; j < 4; ++j) {
        f32x4 kj = *(const f32x4*)(kg + j * 1024 + tid * 4);
        f32x4 vj = *(const f32x4*)(vg + j * 1024 + tid * 4);
        *(bf16x4*)&sK[0][ka0 + j * 1024] = pack4(kj);
#pragma unroll
        for (int i = 0; i < 4; ++i) {
            int d = c4 + i;
            sV[0][d * 64 + ((((j * 2) + (sr0 >> 3)) ^ gkey(d)) << 3) + (sr0 & 7)]
                = bfbits(vj[i]);
        }
    }

    for (int kt = 0; kt < cNT; ++kt) {
        const int cur = kt & 1;
        const bool more = (kt + 1 < cNT);
        const int tnx = more ? kt + 1 : kt;     // clamped: unconditional loads

        // ---- mask(t) as float4 (issued early, consumed after QK MFMAs) ----
        f32x4 mk[2][4];
#pragma unroll
        for (int nt = 0; nt < 4; ++nt) {
            mk[0][nt] = *(const f32x4*)(mrow0 + kt * 64 + nt * 16);
            mk[1][nt] = *(const f32x4*)(mrow1 + kt * 64 + nt * 16);
        }
        // ---- prefetch K/V(t+1) into registers ----
        f32x4 KP[4], VP[4];
        const int tb = tnx * 4096;
#pragma unroll
        for (int j = 0; j < 4; ++j) {
            KP[j] = *(const f32x4*)(kg + tb + j * 1024 + tid * 4);
            VP[j] = *(const f32x4*)(vg + tb + j * 1024 + tid * 4);
        }

        __syncthreads();                        // sK/sV[cur] staged

        // ---- QK (S^T): A=K-frag, B=Q. C: col=ln=qrow, row=quad*4+r=kcol ----
        const unsigned short* sKc = sK[cur];
        float p4[2][4][4];                      // p4[mg][nt][r] = P[mg*16+ln][nt*16+quad*4+r]
#pragma unroll
        for (int nt = 0; nt < 4; ++nt) {
            bf16x8 kf0 = *(const bf16x8*)(
                &sKc[(nt * 16 + ln) * 64 + ((quad ^ (ln & 7)) << 3)]);
            bf16x8 kf1 = *(const bf16x8*)(
                &sKc[(nt * 16 + ln) * 64 + (((4 | quad) ^ (ln & 7)) << 3)]);
            f32x4 c0 = (f32x4){0.f, 0.f, 0.f, 0.f};
            f32x4 c1 = (f32x4){0.f, 0.f, 0.f, 0.f};
            c0 = __builtin_amdgcn_mfma_f32_16x16x32_bf16(kf0, aq[0][0], c0, 0, 0, 0);
            c1 = __builtin_amdgcn_mfma_f32_16x16x32_bf16(kf0, aq[1][0], c1, 0, 0, 0);
            c0 = __builtin_amdgcn_mfma_f32_16x16x32_bf16(kf1, aq[0][1], c0, 0, 0, 0);
            c1 = __builtin_amdgcn_mfma_f32_16x16x32_bf16(kf1, aq[1][1], c1, 0, 0, 0);
#pragma unroll
            for (int r = 0; r < 4; ++r) {
                p4[0][nt][r] = __builtin_amdgcn_exp2f(fmaf(mk[0][nt][r], L2E, c0[r]));
                p4[1][nt][r] = __builtin_amdgcn_exp2f(fmaf(mk[1][nt][r], L2E, c1[r]));
            }
        }
#pragma unroll
        for (int mg = 0; mg < 2; ++mg)
#pragma unroll
            for (int nt = 0; nt < 4; ++nt)
                lsum[mg] += ((p4[mg][nt][0] + p4[mg][nt][1])
                           + (p4[mg][nt][2] + p4[mg][nt][3]));

        // ---- PV: A-frag via ds_bpermute, both nt-planes packed per payload.
        // A[m=ln][k=ks*32+quad*8+j] = P[...][kcol]: src lane (2(quad&1)+(j>>2))*16+ln,
        // plane select (2ks + quad>>1) via packed bf16x2 + shift by dest bit5.
        const unsigned short* sVc = sV[cur];
#pragma unroll
        for (int mg = 0; mg < 2; ++mg)
#pragma unroll
            for (int ks = 0; ks < 2; ++ks) {
                int rA[4], rB[4];
#pragma unroll
                for (int r = 0; r < 4; ++r) {
                    int packed = (int)bfbits(p4[mg][2 * ks][r])
                               | ((int)bfbits(p4[mg][2 * ks + 1][r]) << 16);
                    rA[r] = __builtin_amdgcn_ds_bpermute(permA, packed);
                    rB[r] = __builtin_amdgcn_ds_bpermute(permB, packed);
                }
                bf16x8 ap;
#pragma unroll
                for (int r = 0; r < 4; ++r) {
                    ap[r]     = __builtin_bit_cast(__bf16, (unsigned short)(rA[r] >> shft));
                    ap[4 + r] = __builtin_bit_cast(__bf16, (unsigned short)(rB[r] >> shft));
                }
#pragma unroll
                for (int dt = 0; dt < 4; ++dt) {
                    int d = dt * 16 + ln;
                    bf16x8 bv = *(const bf16x8*)(
                        &sVc[d * 64 + ((((ks << 2) | quad) ^ gkey(d)) << 3)]);
                    acc[mg][dt] = __builtin_amdgcn_mfma_f32_16x16x32_bf16(ap, bv, acc[mg][dt], 0, 0, 0);
                }
            }

        // ---- stage prefetched tile into other buffer ----
        // safe: buffer cur^1's readers (tile t-1) finished before this barrier
        if (more) {
            unsigned short* sKn = sK[cur ^ 1];
            unsigned short* sVn = sV[cur ^ 1];
#pragma unroll
            for (int j = 0; j < 4; ++j) {
                *(bf16x4*)&sKn[ka0 + j * 1024] = pack4(KP[j]);
#pragma unroll
                for (int i = 0; i < 4; ++i) {
                    int d = c4 + i;
                    sVn[d * 64 + ((((j * 2) + (sr0 >> 3)) ^ gkey(d)) << 3) + (sr0 & 7)]
                        = bfbits(VP[j][i]);
                }
            }
        }
    }

    // ---- epilogue: lsum quad-reduce + row broadcast, O = acc / l ----
#pragma unroll
    for (int mg = 0; mg < 2; ++mg) {
        float s = lsum[mg];
        s += __shfl_xor(s, 16, 64);
        s += __shfl_xor(s, 32, 64);             // lane (quad,ln): rowsum(mg*16+ln)
        float rs = 1.0f / s;
        float rl[4];
#pragma unroll
        for (int r = 0; r < 4; ++r)
            rl[r] = __shfl(rs, quad * 4 + r, 64);   // 1/rowsum for row quad*4+r
#pragma unroll
        for (int dt = 0; dt < 4; ++dt)
#pragma unroll
            for (int r = 0; r < 4; ++r)
                out[((size_t)bh * cS + qb + wv * 32 + mg * 16 + quad * 4 + r) * cD
                    + dt * 16 + ln] = acc[mg][dt][r] * rl[r];
    }
}

extern "C" void kernel_launch(void* const* d_in, const int* in_sizes, int n_in,
                              void* d_out, int out_size, void* d_ws, size_t ws_size,
                              hipStream_t stream) {
    const float* q = (const float*)d_in[0];
    const float* k = (const float*)d_in[1];
    const float* v = (const float*)d_in[2];
    const float* m = (const float*)d_in[3];
    float* o = (float*)d_out;
    sdpa_flash_kernel<<<dim3(512), 256, 0, stream>>>(q, k, v, m, o);
}